// Round 4
// baseline (3222.627 us; speedup 1.0000x reference)
//
#include <hip/hip_runtime.h>
#include <cstdint>
#include <cstddef>

// Problem constants (fixed by setup_inputs)
#define HDIM 768
#define VOCAB 32000
#define NGATES 5
#define NJ 30
#define NB 16
#define NS 512
#define NBJ (NB*NJ)      // 480
#define G3 2304          // 3*H
#define PR 608           // padded state rows (max A-row read = 384+127 = 511)
#define NBV 250          // vocab n-blocks

typedef _Float16 f16;
typedef _Float16 f16x8 __attribute__((ext_vector_type(8)));
typedef float f32x4 __attribute__((ext_vector_type(4)));

#define GLOBAL_AS __attribute__((address_space(1)))
#define LDS_AS    __attribute__((address_space(3)))

// ---------------- fp32 -> fp16 cast (plain) ----------------
__global__ void k_cast(const float* __restrict__ src, f16* __restrict__ dst, int n) {
    for (int i = blockIdx.x*256 + threadIdx.x; i < n; i += gridDim.x*256)
        dst[i] = (f16)src[i];
}

// ---------------- fp32 -> fp16 hi/lo split cast ----------------
__global__ void k_cast_split(const float* __restrict__ src, f16* __restrict__ hi,
                             f16* __restrict__ lo, int n) {
    for (int i = blockIdx.x*256 + threadIdx.x; i < n; i += gridDim.x*256) {
        float v = src[i];
        f16 h = (f16)v;
        hi[i] = h;
        lo[i] = (f16)(v - (float)h);
    }
}

// ---------------- init w = sum of slot embeddings, h = hidden ----------------
__global__ void k_init_state(const float* __restrict__ E, const int* __restrict__ slot,
                             const float* __restrict__ hidden,
                             f16* __restrict__ w_hi, f16* __restrict__ w_lo,
                             float* __restrict__ h,
                             f16* __restrict__ h_hi, f16* __restrict__ h_lo) {
    int total = NBJ*HDIM;
    for (int i = blockIdx.x*256 + threadIdx.x; i < total; i += gridDim.x*256) {
        int hh = i % HDIM, row = i / HDIM;
        int b = row / NJ, j = row % NJ;
        float s = 0.f;
        #pragma unroll
        for (int l = 0; l < 4; ++l) s += E[(long)slot[j*4+l]*HDIM + hh];
        f16 sh = (f16)s;
        w_hi[i] = sh; w_lo[i] = (f16)(s - (float)sh);
        float hv = hidden[b*HDIM + hh];
        h[i] = hv;
        f16 hh16 = (f16)hv;
        h_hi[i] = hh16; h_lo[i] = (f16)(hv - (float)hh16);
    }
}

// ---------------- unified split-f16 MFMA GEMM, C = A * B^T ----------------
// BM=BN=128, BK=64, 256 threads = 4 waves (2x2), wave tile 64x64.
// batch via blockIdx.z with element strides aBS/bBS/cBS.
// Staging via global_load_lds width-16 into frag-major LDS [c][row][8].
// A must be readable for rows m0..m0+127 (caller pads); C guarded by M.
// If Ch != nullptr: C stored as f16 (and psum partials use the f16-rounded value).
// If psum != nullptr: per-block rowwise sum(exp(C)) into psum[by*512+row].
__launch_bounds__(256)
__global__ void k_gemm(const f16* __restrict__ Ah, const f16* __restrict__ Al,
                       const f16* __restrict__ Bh, const f16* __restrict__ Bl,
                       float* __restrict__ Cf, f16* __restrict__ Ch,
                       float* __restrict__ psum,
                       int M, long ldc, long coff, int kdim, int nspan,
                       long aBS, long bBS, long cBS) {
    __shared__ f16 a_lds[8][128][8];   // 16 KB
    __shared__ f16 b_lds[8][128][8];   // 16 KB
    __shared__ float sbuf[2][128];

    const int tid = threadIdx.x;
    const int z = blockIdx.z;
    const int m0 = blockIdx.x*128, n0 = blockIdx.y*128;
    const int w = tid >> 6, lane = tid & 63;
    const int wm = (w >> 1)*64, wn = (w & 1)*64;
    const int lr = lane & 15, lg = lane >> 4;

    f32x4 acc[4][4] = {};

    for (int sp = 0; sp < nspan; ++sp) {
        const f16* Ap = ((sp < 2) ? Ah : Al) + (long)z*aBS;
        const f16* Bp = ((sp == 1) ? Bl : Bh) + (long)z*bBS;
        for (int kc = 0; kc < kdim; kc += 64) {
            #pragma unroll
            for (int i = 0; i < 4; ++i) {
                const int idx = w*4 + i;                  // 0..15
                const int c = idx >> 1;                    // k-octet
                const int rl = (idx & 1)*64 + lane;        // row 0..127
                const f16* ga = Ap + (long)(m0 + rl)*kdim + kc + c*8;
                const f16* gb = Bp + (long)(n0 + rl)*kdim + kc + c*8;
                __builtin_amdgcn_global_load_lds(
                    (const GLOBAL_AS unsigned int*)ga,
                    (LDS_AS unsigned int*)((char*)&a_lds[0][0][0] + idx*1024), 16, 0, 0);
                __builtin_amdgcn_global_load_lds(
                    (const GLOBAL_AS unsigned int*)gb,
                    (LDS_AS unsigned int*)((char*)&b_lds[0][0][0] + idx*1024), 16, 0, 0);
            }
            __syncthreads();
            #pragma unroll
            for (int kk = 0; kk < 2; ++kk) {
                const int c = kk*4 + lg;
                f16x8 af[4], bf[4];
                #pragma unroll
                for (int mi = 0; mi < 4; ++mi) af[mi] = *(const f16x8*)&a_lds[c][wm + mi*16 + lr][0];
                #pragma unroll
                for (int nf = 0; nf < 4; ++nf) bf[nf] = *(const f16x8*)&b_lds[c][wn + nf*16 + lr][0];
                #pragma unroll
                for (int mi = 0; mi < 4; ++mi)
                    #pragma unroll
                    for (int nf = 0; nf < 4; ++nf)
                        acc[mi][nf] = __builtin_amdgcn_mfma_f32_16x16x32_f16(af[mi], bf[nf], acc[mi][nf], 0, 0, 0);
            }
            __syncthreads();
        }
    }

    // C write: layout col=lane&15, row=(lane>>4)*4+reg
    if (Ch != nullptr) {
        f16* Cb = Ch + (long)z*cBS + coff;
        #pragma unroll
        for (int mi = 0; mi < 4; ++mi)
            #pragma unroll
            for (int nf = 0; nf < 4; ++nf) {
                int col = n0 + wn + nf*16 + lr;
                int rowb = m0 + wm + mi*16 + lg*4;
                #pragma unroll
                for (int r = 0; r < 4; ++r) {
                    int row = rowb + r;
                    if (row < M) Cb[(long)row*ldc + col] = (f16)acc[mi][nf][r];
                }
            }
    } else {
        float* Cb = Cf + (long)z*cBS + coff;
        #pragma unroll
        for (int mi = 0; mi < 4; ++mi)
            #pragma unroll
            for (int nf = 0; nf < 4; ++nf) {
                int col = n0 + wn + nf*16 + lr;
                int rowb = m0 + wm + mi*16 + lg*4;
                #pragma unroll
                for (int r = 0; r < 4; ++r) {
                    int row = rowb + r;
                    if (row < M) Cb[(long)row*ldc + col] = acc[mi][nf][r];
                }
            }
    }

    // fused row-sumexp over the f16-rounded logits (vocab softmax denominator partials)
    if (psum != nullptr) {
        #pragma unroll
        for (int mi = 0; mi < 4; ++mi) {
            #pragma unroll
            for (int r = 0; r < 4; ++r) {
                float s = 0.f;
                #pragma unroll
                for (int nf = 0; nf < 4; ++nf) s += expf((float)(f16)acc[mi][nf][r]);
                s += __shfl_xor(s, 1); s += __shfl_xor(s, 2);
                s += __shfl_xor(s, 4); s += __shfl_xor(s, 8);
                if (lr == 0) sbuf[w & 1][wm + mi*16 + lg*4 + r] = s;
            }
        }
        __syncthreads();
        if (tid < 128)
            psum[(long)blockIdx.y*512 + m0 + tid] = sbuf[0][tid] + sbuf[1][tid];
    }
}

// ---------------- GRU elementwise ----------------
__global__ void k_gru_elem(const float* __restrict__ gi, const float* __restrict__ gh,
                           const float* __restrict__ bih, const float* __restrict__ bhh,
                           float* __restrict__ h, f16* __restrict__ h_hi, f16* __restrict__ h_lo) {
    int total = NBJ*HDIM;
    for (int i = blockIdx.x*256 + threadIdx.x; i < total; i += gridDim.x*256) {
        int c = i % HDIM; long row = i / HDIM;
        long base = row*G3;
        float r = gi[base + c]        + bih[c]        + gh[base + c]        + bhh[c];
        float z = gi[base + 768 + c]  + bih[768 + c]  + gh[base + 768 + c]  + bhh[768 + c];
        float hn = gh[base + 1536 + c] + bhh[1536 + c];
        float in_ = gi[base + 1536 + c] + bih[1536 + c];
        r = 1.f/(1.f + expf(-r));
        z = 1.f/(1.f + expf(-z));
        float n = tanhf(in_ + r*hn);
        float hv = (1.f - z)*n + z*h[i];
        h[i] = hv;
        f16 hh16 = (f16)hv;
        h_hi[i] = hh16; h_lo[i] = (f16)(hv - (float)hh16);
    }
}

// ---------------- attention scores: ae[row][s] = h[row] . enc[b][s][:] (fp32) ----------------
__launch_bounds__(256)
__global__ void k_attn(const float* __restrict__ h, const float* __restrict__ enc,
                       float* __restrict__ attn_e) {
    __shared__ float h_lds[NJ][64];
    __shared__ float e_lds[64][65];   // +1 pad -> conflict-free
    const int b = blockIdx.x, st = blockIdx.y;
    const int s0 = st*64;
    const int tid = threadIdx.x;
    const int s = tid & 63, jg = tid >> 6;   // jg uniform per wave
    float acc[8] = {};
    for (int kc = 0; kc < HDIM; kc += 64) {
        for (int idx = tid; idx < NJ*64; idx += 256) {
            int j = idx >> 6, k = idx & 63;
            h_lds[j][k] = h[((long)(b*NJ + j))*HDIM + kc + k];
        }
        #pragma unroll
        for (int i = 0; i < 4; ++i) {
            int id = tid + i*256;
            int ss = id >> 4, kq = (id & 15)*4;
            float4 v = *(const float4*)&enc[((long)b*NS + s0 + ss)*HDIM + kc + kq];
            e_lds[ss][kq+0] = v.x; e_lds[ss][kq+1] = v.y;
            e_lds[ss][kq+2] = v.z; e_lds[ss][kq+3] = v.w;
        }
        __syncthreads();
        for (int k = 0; k < 64; ++k) {
            float e = e_lds[s][k];
            #pragma unroll
            for (int i = 0; i < 8; ++i) {
                int j = jg + i*4;
                if (j < NJ) acc[i] += h_lds[j][k]*e;
            }
        }
        __syncthreads();
    }
    #pragma unroll
    for (int i = 0; i < 8; ++i) {
        int j = jg + i*4;
        if (j < NJ) attn_e[((long)(b*NJ + j))*NS + s0 + s] = acc[i];
    }
}

// ---------------- fused: masked softmax (in place) + context (LDS) + p_gen + gates ----------------
__launch_bounds__(256)
__global__ void k_smctxpg(float* __restrict__ ae, const int* __restrict__ masks,
                          const float* __restrict__ enc,
                          const f16* __restrict__ w_hi, const f16* __restrict__ w_lo,
                          const float* __restrict__ h,
                          const float* __restrict__ Wgen, const float* __restrict__ bgen,
                          const float* __restrict__ Wgate, const float* __restrict__ bgate,
                          float* __restrict__ pgen, float* __restrict__ out_gates, int do_gate) {
    const int row = blockIdx.x, tid = threadIdx.x;
    const int b = row / NJ;
    __shared__ float red[256];
    __shared__ float ah_l[NS];
    __shared__ float ctx_l[HDIM];

    // --- masked softmax over S ---
    float x0 = ae[(long)row*NS + tid];
    float x1 = ae[(long)row*NS + tid + 256];
    if (masks[b*NS + tid]       != 1) x0 = -1e9f;
    if (masks[b*NS + tid + 256] != 1) x1 = -1e9f;
    red[tid] = fmaxf(x0, x1); __syncthreads();
    for (int o = 128; o > 0; o >>= 1) { if (tid < o) red[tid] = fmaxf(red[tid], red[tid+o]); __syncthreads(); }
    float m = red[0]; __syncthreads();
    float e0 = expf(x0 - m), e1 = expf(x1 - m);
    red[tid] = e0 + e1; __syncthreads();
    for (int o = 128; o > 0; o >>= 1) { if (tid < o) red[tid] += red[tid+o]; __syncthreads(); }
    float inv = 1.f/red[0];
    float p0 = e0*inv, p1 = e1*inv;
    ae[(long)row*NS + tid]       = p0;
    ae[(long)row*NS + tid + 256] = p1;
    ah_l[tid] = p0; ah_l[tid + 256] = p1;
    __syncthreads();

    // --- context into LDS: ctx[hh] = sum_s ah[s] * enc[b][s][hh] ---
    const float* eb = enc + (long)b*NS*HDIM;
    float c0 = 0.f, c1 = 0.f, c2 = 0.f;
    for (int s = 0; s < NS; ++s) {
        float a = ah_l[s];
        const float* er = eb + (long)s*HDIM;
        c0 += a*er[tid]; c1 += a*er[tid + 256]; c2 += a*er[tid + 512];
    }
    ctx_l[tid] = c0; ctx_l[tid + 256] = c1; ctx_l[tid + 512] = c2;
    __syncthreads();

    // --- p_gen = sigmoid([w,h,ctx] . Wgen + b) ---
    float acc = 0.f;
    for (int x = tid; x < HDIM; x += 256) {
        float wv = (float)w_hi[(long)row*HDIM + x] + (float)w_lo[(long)row*HDIM + x];
        acc += wv*Wgen[x] + h[(long)row*HDIM + x]*Wgen[768 + x] + ctx_l[x]*Wgen[1536 + x];
    }
    red[tid] = acc; __syncthreads();
    for (int o = 128; o > 0; o >>= 1) { if (tid < o) red[tid] += red[tid+o]; __syncthreads(); }
    if (tid == 0) pgen[row] = 1.f/(1.f + expf(-(red[0] + bgen[0])));

    // --- gates from context at t==0 ---
    if (do_gate) {
        for (int g = 0; g < NGATES; ++g) {
            __syncthreads();
            float a = 0.f;
            for (int x = tid; x < HDIM; x += 256) a += ctx_l[x]*Wgate[x*NGATES + g];
            red[tid] = a; __syncthreads();
            for (int o = 128; o > 0; o >>= 1) { if (tid < o) red[tid] += red[tid+o]; __syncthreads(); }
            if (tid == 0) out_gates[row*NGATES + g] = red[0] + bgate[g];
        }
    }
}

// ---------------- scale: p = pgen * exp(l16)/denom, argmax partials ----------------
// grid (480, 8): row, col-chunk of 4000
__launch_bounds__(256)
__global__ void k_scale(const f16* __restrict__ l16, float* __restrict__ out,
                        long ldrow, long coff,
                        const float* __restrict__ psum, const float* __restrict__ pgen,
                        unsigned long long* __restrict__ pamax) {
    const int row = blockIdx.x, c = blockIdx.y, tid = threadIdx.x;
    __shared__ float red[256];
    // denominator = sum of 250 per-block partials (L2-hot)
    float s = 0.f;
    for (int nb = tid; nb < NBV; nb += 256) s += psum[(long)nb*512 + row];
    red[tid] = s; __syncthreads();
    for (int o = 128; o > 0; o >>= 1) { if (tid < o) red[tid] += red[tid+o]; __syncthreads(); }
    const float scale = pgen[row] / red[0];

    const f16* lb = l16 + (long)row*VOCAB;
    float* ob = out + (long)row*ldrow + coff;
    const int v0 = c*4000;
    float bv = -1.f; int bi = 0x7FFFFFFF;
    for (int v = v0 + tid; v < v0 + 4000; v += 256) {
        float val = scale*expf((float)lb[v]);
        ob[v] = val;
        if (val > bv) { bv = val; bi = v; }   // strict ">" keeps smallest index per thread
    }
    __shared__ float rv[256]; __shared__ int ri[256];
    rv[tid] = bv; ri[tid] = bi; __syncthreads();
    for (int o = 128; o > 0; o >>= 1) {
        if (tid < o) {
            float v2 = rv[tid+o]; int i2 = ri[tid+o];
            if (v2 > rv[tid] || (v2 == rv[tid] && i2 < ri[tid])) { rv[tid] = v2; ri[tid] = i2; }
        }
        __syncthreads();
    }
    if (tid == 0)
        pamax[(long)row*8 + c] = ((unsigned long long)__float_as_uint(rv[0]) << 32)
                               | (unsigned long long)(0xFFFFFFFFu - (unsigned)ri[0]);
}

// ---------------- scatter + final argmax + next-w gather ----------------
__launch_bounds__(256)
__global__ void k_scatter(float* __restrict__ pts, long ldrow, long coff,
                          const int* __restrict__ ids, const float* __restrict__ ah,
                          const float* __restrict__ pgen,
                          const unsigned long long* __restrict__ pamax,
                          const float* __restrict__ E,
                          f16* __restrict__ w_hi, f16* __restrict__ w_lo) {
    const int row = blockIdx.x, tid = threadIdx.x;
    const int b = row / NJ;
    float* base = pts + (long)row*ldrow + coff;
    const float cp = 1.f - pgen[row];
    float sv = -1.f; int si = 0x7FFFFFFF;
    for (int ss = tid; ss < NS; ss += 256) {
        int id = ids[(long)b*NS + ss];
        float add = cp * ah[(long)row*NS + ss];
        float old = atomicAdd(base + id, add);
        float cand = old + add;   // temporally-last add on an address yields its true final value
        if (cand > sv || (cand == sv && id < si)) { sv = cand; si = id; }
    }
    __shared__ float rv[256]; __shared__ int ri[256];
    rv[tid] = sv; ri[tid] = si; __syncthreads();
    for (int o = 128; o > 0; o >>= 1) {
        if (tid < o) {
            float v2 = rv[tid+o]; int i2 = ri[tid+o];
            if (v2 > rv[tid] || (v2 == rv[tid] && i2 < ri[tid])) { rv[tid] = v2; ri[tid] = i2; }
        }
        __syncthreads();
    }
    __shared__ int bidx;
    if (tid == 0) {
        float vv = rv[0]; int ii = ri[0];
        #pragma unroll
        for (int cc = 0; cc < 8; ++cc) {
            unsigned long long pk = pamax[(long)row*8 + cc];
            float pv = __uint_as_float((unsigned)(pk >> 32));
            int pi = (int)(0xFFFFFFFFu - (unsigned)(pk & 0xFFFFFFFFu));
            if (pv > vv || (pv == vv && pi < ii)) { vv = pv; ii = pi; }
        }
        bidx = ii;
    }
    __syncthreads();
    const int idx = bidx;
    for (int x = tid; x < HDIM; x += 256) {
        float ev = E[(long)idx*HDIM + x];
        f16 eh = (f16)ev;
        w_hi[(long)row*HDIM + x] = eh;
        w_lo[(long)row*HDIM + x] = (f16)(ev - (float)eh);
    }
}

// ---------------- host ----------------
extern "C" void kernel_launch(void* const* d_in, const int* in_sizes, int n_in,
                              void* d_out, int out_size, void* d_ws, size_t ws_size,
                              hipStream_t stream) {
    const int*   input_ids = (const int*)  d_in[0];
    const float* enc       = (const float*)d_in[1];
    const float* hidden    = (const float*)d_in[2];
    const int*   masks     = (const int*)  d_in[3];
    const int*   slot      = (const int*)  d_in[4];
    const float* E     = (const float*)d_in[6];
    const float* Wih   = (const float*)d_in[7];
    const float* Whh   = (const float*)d_in[8];
    const float* bih   = (const float*)d_in[9];
    const float* bhh   = (const float*)d_in[10];
    const float* Wgen  = (const float*)d_in[11];
    const float* bgen  = (const float*)d_in[12];
    const float* Wgate = (const float*)d_in[13];
    const float* bgate = (const float*)d_in[14];

    const int ml = (out_size / NBJ - NGATES) / VOCAB;   // = 8
    float* out = (float*)d_out;
    float* gates_out = out + (long)NBJ*ml*VOCAB;

    // workspace carve (256B aligned)
    char* ws = (char*)d_ws;
    auto carve = [&](size_t bytes) { char* p = ws; ws += (bytes + 255) & ~(size_t)255; return p; };
    f16*   E16   = (f16*)carve((size_t)VOCAB*HDIM*2);
    f16*   WH2   = (f16*)carve((size_t)2*G3*HDIM*2);   // WihH | WhhH (contiguous for batch-z)
    f16*   WL2   = (f16*)carve((size_t)2*G3*HDIM*2);
    f16*   SH    = (f16*)carve((size_t)2*PR*HDIM*2);   // wH | hH (padded rows)
    f16*   SL    = (f16*)carve((size_t)2*PR*HDIM*2);
    float* gigh  = (float*)carve((size_t)2*NBJ*G3*4);  // gi | gh
    float* hbuf  = (float*)carve((size_t)NBJ*HDIM*4);
    float* ae    = (float*)carve((size_t)NBJ*NS*4);
    f16*   l16   = (f16*)carve((size_t)NBJ*VOCAB*2);   // per-step vocab logits (f16)
    float* pgen  = (float*)carve((size_t)NBJ*4);
    float* ps    = (float*)carve((size_t)NBV*512*4);
    unsigned long long* pamax = (unsigned long long*)carve((size_t)NBJ*8*8);

    f16* WihH = WH2;  f16* WihL = WL2;
    f16* wH = SH;     f16* wL = SL;
    f16* hH = SH + (size_t)PR*HDIM;
    f16* hL = SL + (size_t)PR*HDIM;
    float* gi = gigh; float* gh = gigh + (size_t)NBJ*G3;
    (void)gi; (void)gh;

    k_cast<<<8192, 256, 0, stream>>>(E, E16, VOCAB*HDIM);
    k_cast_split<<<2048, 256, 0, stream>>>(Wih, WihH, WihL, G3*HDIM);
    k_cast_split<<<2048, 256, 0, stream>>>(Whh, WH2 + (size_t)G3*HDIM, WL2 + (size_t)G3*HDIM, G3*HDIM);
    k_init_state<<<1440, 256, 0, stream>>>(E, slot, hidden, wH, wL, hbuf, hH, hL);

    const long ldrow = (long)ml*VOCAB;
    for (int t = 0; t < ml; ++t) {
        // GRU gates, one launch: z=0: gi = w@Wih^T, z=1: gh = h@Whh^T (split-f16, 3 spans)
        k_gemm<<<dim3(4, 18, 2), 256, 0, stream>>>(wH, wL, WihH, WihL, gigh, nullptr, nullptr,
            NBJ, (long)G3, 0, HDIM, 3, (long)PR*HDIM, (long)G3*HDIM, (long)NBJ*G3);
        k_gru_elem<<<1440, 256, 0, stream>>>(gigh, gigh + (size_t)NBJ*G3, bih, bhh, hbuf, hH, hL);
        // attention scores (fp32)
        k_attn<<<dim3(NB, 8), 256, 0, stream>>>(hbuf, enc, ae);
        // fused softmax + context + p_gen (+ gates at t==0)
        k_smctxpg<<<NBJ, 256, 0, stream>>>(ae, masks, enc, wH, wL, hbuf,
                                           Wgen, bgen, Wgate, bgate,
                                           pgen, gates_out, t == 0 ? 1 : 0);
        // vocab logits (f16) + fused row-sumexp partials (no-max softmax)
        k_gemm<<<dim3(4, NBV, 1), 256, 0, stream>>>(hH, hL, E16, nullptr, nullptr, l16, ps,
            NBJ, (long)VOCAB, 0, HDIM, 1, 0, 0, 0);
        // parallel scale + per-chunk argmax
        k_scale<<<dim3(NBJ, 8), 256, 0, stream>>>(l16, out, ldrow, (long)t*VOCAB, ps, pgen, pamax);
        // pointer scatter + final argmax + next-w gather
        k_scatter<<<NBJ, 256, 0, stream>>>(out, ldrow, (long)t*VOCAB, input_ids, ae, pgen,
                                           pamax, E, wH, wL);
    }
}